// Round 4
// baseline (210.408 us; speedup 1.0000x reference)
//
#include <hip/hip_runtime.h>
#include <math.h>

#define B_G   256
#define IN_D  128
#define FD    256
#define HID   256
#define OUT_D 128
#define TXT   512

typedef short bf16x8 __attribute__((ext_vector_type(8)));
typedef float f32x4  __attribute__((ext_vector_type(4)));

// ---------------------------------------------------------------------------
// bf16 split helpers (RNE)
// ---------------------------------------------------------------------------
__device__ __forceinline__ unsigned bf_rne(float x) {
    unsigned u = __float_as_uint(x);
    u += 0x7fffu + ((u >> 16) & 1u);
    return u >> 16;
}
__device__ __forceinline__ float bf_to_f(unsigned h) {
    return __uint_as_float(h << 16);
}
__device__ __forceinline__ void split2(float a0, float a1, unsigned& hp, unsigned& lp) {
    unsigned h0 = bf_rne(a0), h1 = bf_rne(a1);
    float r0 = a0 - bf_to_f(h0), r1 = a1 - bf_to_f(h1);
    hp = h0 | (h1 << 16);
    lp = bf_rne(r0) | (bf_rne(r1) << 16);
}
// split 8 floats -> hi/lo bf16x8 fragments (in registers, no LDS)
__device__ __forceinline__ void split8(const float* z, bf16x8& hf, bf16x8& lf) {
    uint4 h, l;
    split2(z[0], z[1], h.x, l.x);
    split2(z[2], z[3], h.y, l.y);
    split2(z[4], z[5], h.z, l.z);
    split2(z[6], z[7], h.w, l.w);
    hf = __builtin_bit_cast(bf16x8, h);
    lf = __builtin_bit_cast(bf16x8, l);
}

// ---------------------------------------------------------------------------
// Kernel A (grid 265): fused prep.
//  blocks 0..255  : q_b = te@Wq+bq ; qk_b = Wk@q_b ; zero hsum[b]
//  blocks 256..263: split W0/W2 into tight fragment-layout hi/lo bf16 buffers
//                   W0s[kc=4][col=256][kk=32], W2s[kc=8][col=128][kk=32]
//  block  264     : parallel scan of lens -> offsets
// ---------------------------------------------------------------------------
__global__ __launch_bounds__(256) void k_prepA(
    const float* __restrict__ text_emb, const float* __restrict__ Wq,
    const float* __restrict__ bq, const float* __restrict__ Wk,
    const float* __restrict__ W0, const float* __restrict__ W2,
    const int* __restrict__ lens,
    float* __restrict__ qk, int* __restrict__ offsets, float* __restrict__ hsum,
    unsigned short* __restrict__ W0sH, unsigned short* __restrict__ W0sL,
    unsigned short* __restrict__ W2sH, unsigned short* __restrict__ W2sL)
{
    int blk = blockIdx.x, t = threadIdx.x;
    __shared__ float te[TXT];
    __shared__ float q[FD];
    __shared__ int   sc[B_G];

    if (blk < 256) {
        int b = blk;
        hsum[b * FD + t] = 0.f;
        for (int i = t; i < TXT; i += 256) te[i] = text_emb[(size_t)b * TXT + i];
        __syncthreads();
        float acc = bq[t];
        for (int k = 0; k < TXT; k++) acc = fmaf(te[k], Wq[k * FD + t], acc);
        q[t] = acc;
        __syncthreads();
        float a2 = 0.f;
        for (int f = 0; f < FD; f++) a2 = fmaf(Wk[t * FD + f], q[f], a2);
        qk[b * FD + t] = a2;
    } else if (blk < 264) {
        int e = (blk - 256) * 256 + t;   // 0..2047
        if (e < 1024) {
            int kc = e >> 8, c = e & 255;
            size_t base = (size_t)(kc * 256 + c) * 32;
            for (int kk = 0; kk < 32; kk++) {
                float v = W0[(size_t)(kc * 32 + kk) * FD + c];
                unsigned h = bf_rne(v);
                float r = v - bf_to_f(h);
                W0sH[base + kk] = (unsigned short)h;
                W0sL[base + kk] = (unsigned short)bf_rne(r);
            }
        } else {
            int e2 = e - 1024;
            int kc = e2 >> 7, c = e2 & 127;
            size_t base = (size_t)(kc * 128 + c) * 32;
            for (int kk = 0; kk < 32; kk++) {
                float v = W2[(size_t)(kc * 32 + kk) * OUT_D + c];
                unsigned h = bf_rne(v);
                float r = v - bf_to_f(h);
                W2sH[base + kk] = (unsigned short)h;
                W2sL[base + kk] = (unsigned short)bf_rne(r);
            }
        }
    } else {
        sc[t] = lens[t];
        __syncthreads();
        for (int d = 1; d < 256; d <<= 1) {
            int v = (t >= d) ? sc[t - d] : 0;
            __syncthreads();
            sc[t] += v;
            __syncthreads();
        }
        offsets[t + 1] = sc[t];
        if (t == 0) offsets[0] = 0;
    }
}

// ---------------------------------------------------------------------------
// K1: bf16x3 MFMA, fully LDS-free K-loop.
//  A-fragments: X loaded global->reg (32 B/lane per (i,kc)), split in-reg.
//  B-fragments: W0s global->reg (L2-hot, fragment-contiguous).
//  No staging LDS, no barriers in the K-loop. ~3 KB LDS for epilogue only.
// ---------------------------------------------------------------------------
__global__ __launch_bounds__(256, 2) void k_l0_mfma(
    const float* __restrict__ X,
    const unsigned short* __restrict__ W0sH, const unsigned short* __restrict__ W0sL,
    const float* __restrict__ b0, const float* __restrict__ qk,
    const int* __restrict__ offsets,
    float* __restrict__ scores, float* __restrict__ hsum)
{
    int b = blockIdx.y;
    int off = offsets[b], len = offsets[b + 1] - off;
    int n0 = blockIdx.x * 64;
    if (n0 >= len) return;
    int nvalid = min(64, len - n0);

    __shared__ float qks[FD];
    __shared__ float bsh[FD];
    __shared__ float red[4][64];

    int tid = threadIdx.x;
    int lane = tid & 63, w = tid >> 6;
    int ln = lane & 15, quad = lane >> 4;

    qks[tid] = qk[b * FD + tid];
    bsh[tid] = b0[tid];

    const float* Xbase = X + (size_t)(off + n0) * IN_D;

    f32x4 acc[4][4] = {};
#pragma unroll
    for (int kc = 0; kc < 4; kc++) {
        bf16x8 AH[4], AL[4], BH[4], BL[4];
#pragma unroll
        for (int i = 0; i < 4; i++) {
            int node = 16 * i + ln;
            float xv[8];
            if (node < nvalid) {
                const float4* p = (const float4*)(Xbase + (size_t)node * IN_D + kc * 32 + quad * 8);
                float4 v0 = p[0], v1 = p[1];
                xv[0] = v0.x; xv[1] = v0.y; xv[2] = v0.z; xv[3] = v0.w;
                xv[4] = v1.x; xv[5] = v1.y; xv[6] = v1.z; xv[7] = v1.w;
            } else {
#pragma unroll
                for (int q2 = 0; q2 < 8; q2++) xv[q2] = 0.f;
            }
            split8(xv, AH[i], AL[i]);
        }
#pragma unroll
        for (int j = 0; j < 4; j++) {
            int c = 64 * w + 16 * j + ln;
            size_t base = (size_t)(kc * 256 + c) * 32 + quad * 8;
            BH[j] = *(const bf16x8*)&W0sH[base];
            BL[j] = *(const bf16x8*)&W0sL[base];
        }
#pragma unroll
        for (int i = 0; i < 4; i++)
#pragma unroll
            for (int j = 0; j < 4; j++) {
                acc[i][j] = __builtin_amdgcn_mfma_f32_16x16x32_bf16(AH[i], BH[j], acc[i][j], 0, 0, 0);
                acc[i][j] = __builtin_amdgcn_mfma_f32_16x16x32_bf16(AH[i], BL[j], acc[i][j], 0, 0, 0);
                acc[i][j] = __builtin_amdgcn_mfma_f32_16x16x32_bf16(AL[i], BH[j], acc[i][j], 0, 0, 0);
            }
    }
    __syncthreads();   // qks/bsh written by all threads -> visible for epilogue

    // ---- epilogue: bias+relu+mask -> score partials & column sums ----
    float sp[4][4];
    float cs[4] = {0.f, 0.f, 0.f, 0.f};
#pragma unroll
    for (int i = 0; i < 4; i++)
#pragma unroll
        for (int r = 0; r < 4; r++) sp[i][r] = 0.f;

#pragma unroll
    for (int i = 0; i < 4; i++)
#pragma unroll
        for (int j = 0; j < 4; j++) {
            int c = 64 * w + 16 * j + ln;
            float bb = bsh[c], qv = qks[c];
#pragma unroll
            for (int r = 0; r < 4; r++) {
                int node = 16 * i + 4 * quad + r;
                float h = acc[i][j][r] + bb;
                h = (h > 0.f && node < nvalid) ? h : 0.f;
                sp[i][r] = fmaf(h, qv, sp[i][r]);
                cs[j] += h;
            }
        }
#pragma unroll
    for (int i = 0; i < 4; i++)
#pragma unroll
        for (int r = 0; r < 4; r++) {
            float s = sp[i][r];
            s += __shfl_xor(s, 1); s += __shfl_xor(s, 2);
            s += __shfl_xor(s, 4); s += __shfl_xor(s, 8);
            sp[i][r] = s;
        }
    if (ln == 0) {
#pragma unroll
        for (int i = 0; i < 4; i++)
#pragma unroll
            for (int r = 0; r < 4; r++)
                red[w][16 * i + 4 * quad + r] = sp[i][r];
    }
#pragma unroll
    for (int j = 0; j < 4; j++) {
        float s = cs[j];
        s += __shfl_xor(s, 16); s += __shfl_xor(s, 32);
        if (quad == 0) atomicAdd(&hsum[b * FD + 64 * w + 16 * j + ln], s);
    }
    __syncthreads();
    if (tid < 64 && tid < nvalid)
        scores[off + n0 + tid] = red[0][tid] + red[1][tid] + red[2][tid] + red[3][tid];
}

// ---------------------------------------------------------------------------
// K2: per-graph softmax stats + w_b = (hsum_b @ Wv + len*bv) @ Wo
// ---------------------------------------------------------------------------
__global__ __launch_bounds__(1024) void k_graph(
    const float* __restrict__ scores, const float* __restrict__ hsum,
    const float* __restrict__ Wv, const float* __restrict__ bv,
    const float* __restrict__ Wo, const int* __restrict__ offsets,
    float* __restrict__ wvec, float* __restrict__ smax, float* __restrict__ dinv)
{
    int b = blockIdx.x, tid = threadIdx.x;
    int t = tid & 255, g = tid >> 8;
    int off = offsets[b], len = offsets[b + 1] - off;
    __shared__ float redm[16], reds[16];
    __shared__ float hs[FD], vs[FD];
    __shared__ float part[4][FD];

    float m = -INFINITY;
    for (int i = tid; i < len; i += 1024) m = fmaxf(m, scores[off + i]);
    for (int d = 1; d < 64; d <<= 1) m = fmaxf(m, __shfl_xor(m, d));
    if ((tid & 63) == 0) redm[tid >> 6] = m;
    __syncthreads();
    m = -INFINITY;
#pragma unroll
    for (int k = 0; k < 16; k++) m = fmaxf(m, redm[k]);

    float s = 0.f;
    for (int i = tid; i < len; i += 1024) s += expf(scores[off + i] - m);
    for (int d = 1; d < 64; d <<= 1) s += __shfl_xor(s, d);
    if ((tid & 63) == 0) reds[tid >> 6] = s;
    if (g == 0) hs[t] = hsum[b * FD + t];
    __syncthreads();
    s = 0.f;
#pragma unroll
    for (int k = 0; k < 16; k++) s += reds[k];

    float acc = (g == 0) ? (float)len * bv[t] : 0.f;
    for (int f = 64 * g; f < 64 * g + 64; f++) acc = fmaf(hs[f], Wv[f * FD + t], acc);
    part[g][t] = acc;
    __syncthreads();
    if (g == 0) vs[t] = part[0][t] + part[1][t] + part[2][t] + part[3][t];
    __syncthreads();
    float a2 = 0.f;
    for (int f = 64 * g; f < 64 * g + 64; f++) a2 = fmaf(vs[f], Wo[f * HID + t], a2);
    part[g][t] = a2;
    __syncthreads();
    if (g == 0) wvec[b * HID + t] = part[0][t] + part[1][t] + part[2][t] + part[3][t];
    if (tid == 0) { smax[b] = m; dinv[b] = 1.0f / s; }
}

// ---------------------------------------------------------------------------
// K3: bf16x3 MFMA, fully LDS-free K-loop.
//  A-fragments computed in-reg: z = relu(p_n * w_k + bo_k); p from 4 scalars,
//  w/bo via 32-B broadcast LDS reads. B-fragments global->reg (L2-hot).
// ---------------------------------------------------------------------------
__global__ __launch_bounds__(256, 2) void k_fin_mfma(
    const float* __restrict__ scores, const float* __restrict__ wvec,
    const float* __restrict__ bo,
    const unsigned short* __restrict__ W2sH, const unsigned short* __restrict__ W2sL,
    const float* __restrict__ b2, const float* __restrict__ smax,
    const float* __restrict__ dinv, const int* __restrict__ offsets,
    float* __restrict__ Y)
{
    int b = blockIdx.y;
    int off = offsets[b], len = offsets[b + 1] - off;
    int n0 = blockIdx.x * 64;
    if (n0 >= len) return;
    int nvalid = min(64, len - n0);

    int tid = threadIdx.x;
    int lane = tid & 63, w = tid >> 6;
    int ln = lane & 15, quad = lane >> 4;

    __shared__ float wsh[HID];
    __shared__ float bosh[HID];
    __shared__ float b2sh[OUT_D];

    wsh[tid] = wvec[b * HID + tid];
    bosh[tid] = bo[tid];
    if (tid < OUT_D) b2sh[tid] = b2[tid];

    float sm = smax[b], di = dinv[b];
    float p[4];
#pragma unroll
    for (int i = 0; i < 4; i++) {
        int node = 16 * i + ln;
        p[i] = (node < nvalid) ? expf(scores[off + n0 + node] - sm) * di : 0.f;
    }
    __syncthreads();

    f32x4 acc[4][2] = {};
#pragma unroll
    for (int kc = 0; kc < 8; kc++) {
        // lane's k-range: kc*32 + quad*8 + 0..7 ; broadcast reads within quad
        float wv[8], bov[8];
        {
            const float4* wp = (const float4*)&wsh[kc * 32 + quad * 8];
            const float4* bp = (const float4*)&bosh[kc * 32 + quad * 8];
            float4 w0 = wp[0], w1 = wp[1], c0 = bp[0], c1 = bp[1];
            wv[0] = w0.x; wv[1] = w0.y; wv[2] = w0.z; wv[3] = w0.w;
            wv[4] = w1.x; wv[5] = w1.y; wv[6] = w1.z; wv[7] = w1.w;
            bov[0] = c0.x; bov[1] = c0.y; bov[2] = c0.z; bov[3] = c0.w;
            bov[4] = c1.x; bov[5] = c1.y; bov[6] = c1.z; bov[7] = c1.w;
        }
        bf16x8 AH[4], AL[4], BH[2], BL[2];
#pragma unroll
        for (int i = 0; i < 4; i++) {
            float z[8];
#pragma unroll
            for (int jj = 0; jj < 8; jj++)
                z[jj] = fmaxf(fmaf(p[i], wv[jj], bov[jj]), 0.f);
            split8(z, AH[i], AL[i]);
        }
#pragma unroll
        for (int j = 0; j < 2; j++) {
            int c = 32 * w + 16 * j + ln;
            size_t base = (size_t)(kc * 128 + c) * 32 + quad * 8;
            BH[j] = *(const bf16x8*)&W2sH[base];
            BL[j] = *(const bf16x8*)&W2sL[base];
        }
#pragma unroll
        for (int i = 0; i < 4; i++)
#pragma unroll
            for (int j = 0; j < 2; j++) {
                acc[i][j] = __builtin_amdgcn_mfma_f32_16x16x32_bf16(AH[i], BH[j], acc[i][j], 0, 0, 0);
                acc[i][j] = __builtin_amdgcn_mfma_f32_16x16x32_bf16(AH[i], BL[j], acc[i][j], 0, 0, 0);
                acc[i][j] = __builtin_amdgcn_mfma_f32_16x16x32_bf16(AL[i], BH[j], acc[i][j], 0, 0, 0);
            }
    }

    // ---- epilogue: + b2, masked store ----
#pragma unroll
    for (int i = 0; i < 4; i++)
#pragma unroll
        for (int j = 0; j < 2; j++) {
            int c = 32 * w + 16 * j + ln;
            float bb = b2sh[c];
#pragma unroll
            for (int r = 0; r < 4; r++) {
                int node = 16 * i + 4 * quad + r;
                if (node < nvalid)
                    Y[(size_t)(off + n0 + node) * OUT_D + c] = acc[i][j][r] + bb;
            }
        }
}

// ---------------------------------------------------------------------------
extern "C" void kernel_launch(void* const* d_in, const int* in_sizes, int n_in,
                              void* d_out, int out_size, void* d_ws, size_t ws_size,
                              hipStream_t stream)
{
    const float* X        = (const float*)d_in[0];
    const float* text_emb = (const float*)d_in[1];
    const int*   lens     = (const int*)d_in[2];
    const float* W0       = (const float*)d_in[3];
    const float* b0       = (const float*)d_in[4];
    const float* Wq       = (const float*)d_in[5];
    const float* bq       = (const float*)d_in[6];
    const float* Wk       = (const float*)d_in[7];
    // d_in[8] = bk : softmax-invariant, unused
    const float* Wv       = (const float*)d_in[9];
    const float* bv       = (const float*)d_in[10];
    const float* Wo       = (const float*)d_in[11];
    const float* bo       = (const float*)d_in[12];
    const float* W2       = (const float*)d_in[13];
    const float* b2       = (const float*)d_in[14];
    float* Y = (float*)d_out;

    char* base = (char*)d_ws;
    size_t o = 0;
    int*   offsets = (int*)(base + o);            o += 1088;
    float* qkbuf   = (float*)(base + o);          o += 262144;
    float* wvec    = (float*)(base + o);          o += 262144;
    float* smaxb   = (float*)(base + o);          o += 1024;
    float* dinvb   = (float*)(base + o);          o += 1024;
    float* hsum    = (float*)(base + o);          o += 262144;
    float* scores  = (float*)(base + o);          o += 262144;
    unsigned short* W0sH = (unsigned short*)(base + o); o += 65536;
    unsigned short* W0sL = (unsigned short*)(base + o); o += 65536;
    unsigned short* W2sH = (unsigned short*)(base + o); o += 65536;
    unsigned short* W2sL = (unsigned short*)(base + o); o += 65536;

    k_prepA<<<265, 256, 0, stream>>>(text_emb, Wq, bq, Wk, W0, W2, lens,
                                     qkbuf, offsets, hsum, W0sH, W0sL, W2sH, W2sL);
    k_l0_mfma<<<dim3(6, B_G), 256, 0, stream>>>(X, W0sH, W0sL, b0, qkbuf, offsets, scores, hsum);
    k_graph<<<B_G, 1024, 0, stream>>>(scores, hsum, Wv, bv, Wo, offsets, wvec, smaxb, dinvb);
    k_fin_mfma<<<dim3(6, B_G), 256, 0, stream>>>(scores, wvec, bo, W2sH, W2sL, b2, smaxb, dinvb, offsets, Y);
}